// Round 8
// baseline (1010.225 us; speedup 1.0000x reference)
//
#include <hip/hip_runtime.h>

// AttentionMatcher R8: direct-from-L2 B-operands + 8 XCD-pinned splits
// (4 blocks/CU) + alpha-skip + in-kernel last-block combine (no 3rd kernel).
// out = gate * softmax(N M^T, diag<-0) M + (1-gate) * N,  n=8192, d=256, fp32.
//
// ws: MhG [n][256] fp16 row-major            (QK B-plane)
//     MtG [n/32 tiles][256 d][32 j] fp16     (PV B-plane, transposed)
//     Ofp 7 fp16 partial O planes (splits 1..7); split-0 partial f32 in d_out
//     MLm/MLl [8][n] f32 running max / sum;  cnt[128] int (memset 0 per launch)
//
// attn: 1024 blocks = 128 q-blocks x 8 splits (s = bid&7 -> XCD-pinned so
//   each XCD's 1MB plane slice stays in its 4MB L2), 256 thr,
//   launch_bounds(256,4) -> 4 blocks/CU (16 waves/CU). BQ=64, BJ=32, 32 tiles.
//   Last split block per q-block merges all 8 partials + gate + blend.

constexpr int EMBED = 256;
constexpr int BQ = 64;
constexpr int BJ = 32;
constexpr int NT = 256;
constexpr int NS = 8;                // j-splits

constexpr int SS_OFF = 0;            // 2 planes x (64 x 36) f32 = 18432 B
constexpr int PH_OFF = 18432;        // 64 x 80 B (32 fp16 + pad)
constexpr int MS_OFF = 23552;
constexpr int LS_OFF = 23808;
constexpr int AS_OFF = 24064;
constexpr int AF_OFF = 24320;        // int aflag[2]
constexpr int LW_OFF = 24328;        // int last-flag
constexpr int LDS_SZ = 24332;        // x4 blocks/CU = 97.3 KB

typedef _Float16 half8 __attribute__((ext_vector_type(8)));
typedef float f32x4 __attribute__((ext_vector_type(4)));
typedef short short8v __attribute__((ext_vector_type(8)));

static __device__ __forceinline__ f32x4 mfma16(half8 a, half8 b, f32x4 c) {
    return __builtin_amdgcn_mfma_f32_16x16x32_f16(a, b, c, 0, 0, 0);
}
static __device__ __forceinline__ short f2h(float x) {
    return (short)__builtin_bit_cast(unsigned short, (_Float16)x);
}

// ---------- prep: fp16 row plane + fp16 transposed tile plane ----------
__global__ void prep(const float* __restrict__ M,
                     short* __restrict__ MhG, short* __restrict__ MtG) {
    __shared__ float L[16 * 260];
    const int r0 = blockIdx.x * 16;
    const int t = threadIdx.x;
    const int pj = t >> 4, pc = (t & 15) * 16;
    {
        const float* src = M + (size_t)(r0 + pj) * EMBED + pc;
        float4 v[4];
        #pragma unroll
        for (int i = 0; i < 4; ++i) v[i] = ((const float4*)src)[i];
        short* hd = MhG + (size_t)(r0 + pj) * EMBED + pc;
        #pragma unroll
        for (int i = 0; i < 2; ++i) {
            float4 a = v[2 * i], b = v[2 * i + 1];
            short8v h;
            h[0]=f2h(a.x); h[1]=f2h(a.y); h[2]=f2h(a.z); h[3]=f2h(a.w);
            h[4]=f2h(b.x); h[5]=f2h(b.y); h[6]=f2h(b.z); h[7]=f2h(b.w);
            *(short8v*)(hd + 8 * i) = h;
        }
        #pragma unroll
        for (int i = 0; i < 4; ++i)
            *(float4*)(L + pj * 260 + pc + 4 * i) = v[i];
    }
    __syncthreads();
    {
        const int d = t;
        const int tile = r0 >> 5, jh = (r0 >> 4) & 1;
        short* dst = MtG + (size_t)tile * (BJ * EMBED) + d * BJ + jh * 16;
        #pragma unroll
        for (int g2 = 0; g2 < 2; ++g2) {
            short8v w;
            #pragma unroll
            for (int e = 0; e < 8; ++e) w[e] = f2h(L[(g2 * 8 + e) * 260 + d]);
            *(short8v*)(dst + g2 * 8) = w;
        }
    }
}

// ---------- fused flash attention + last-block combine ----------
__launch_bounds__(NT, 4)
__global__ void attn(const short* __restrict__ MhG, const short* __restrict__ MtG,
                     const float* __restrict__ Ng, const float* __restrict__ Wg,
                     const float* __restrict__ bg, const float* __restrict__ gb,
                     const int* __restrict__ iseval_p,
                     float* __restrict__ out, short* __restrict__ Ofp,
                     float* __restrict__ MLm, float* __restrict__ MLl,
                     int* __restrict__ cnt, int n)
{
    __shared__ __align__(16) char smem[LDS_SZ];
    float* MS = (float*)(smem + MS_OFF);
    float* LS = (float*)(smem + LS_OFF);
    float* AS = (float*)(smem + AS_OFF);
    int* AFLAG = (int*)(smem + AF_OFF);
    int* LASTW = (int*)(smem + LW_OFF);

    const int t = threadIdx.x, lane = t & 63, wave = t >> 6;
    const int quad = lane >> 4, mn = lane & 15;
    const int bid = blockIdx.x;
    const int s  = bid & (NS - 1);               // split == XCD (bid%8 pinning)
    const int qb = bid >> 3;                     // 0..127
    const int q0 = qb * BQ;
    const int jbase = s * (n / NS);
    const int jb32 = jbase / BJ;
    const int ntiles = (n / NS) / BJ;            // 32
    const int iseval = *iseval_p;
    const int jt = wave & 1, kh = wave >> 1;     // QK roles
    const int dq = wave;                         // PV d-quarter
    const int sq = t >> 2, sh = t & 3;           // softmax roles

    if (t < BQ) { MS[t] = -1e30f; LS[t] = 0.f; }
    if (t < 2) AFLAG[t] = 1;

    // ---- Q fragments fp16 (A-layout): this wave's K-half ----
    half8 Qf[4][4];
    #pragma unroll
    for (int qi = 0; qi < 4; ++qi) {
        const float* np = Ng + (size_t)(q0 + qi * 16 + mn) * EMBED;
        #pragma unroll
        for (int kk = 0; kk < 4; ++kk) {
            const float* p = np + (kh * 4 + kk) * 32 + quad * 8;
            float4 a = *(const float4*)p, b = *(const float4*)(p + 4);
            half8 h;
            h[0]=(_Float16)a.x; h[1]=(_Float16)a.y; h[2]=(_Float16)a.z; h[3]=(_Float16)a.w;
            h[4]=(_Float16)b.x; h[5]=(_Float16)b.y; h[6]=(_Float16)b.z; h[7]=(_Float16)b.w;
            Qf[qi][kk] = h;
        }
    }

    f32x4 O[4][4];
    #pragma unroll
    for (int qi = 0; qi < 4; ++qi)
        #pragma unroll
        for (int dt = 0; dt < 4; ++dt) O[qi][dt] = (f32x4){0.f, 0.f, 0.f, 0.f};

    const short* mhb0 = MhG + (size_t)(jbase + jt * 16 + mn) * EMBED + kh * 128 + quad * 8;
    half8 Bc[4], Bn[4], Mtf[4];
    #pragma unroll
    for (int kk = 0; kk < 4; ++kk) Bc[kk] = *(const half8*)(mhb0 + kk * 32);

    __syncthreads();

    for (int tile = 0; tile < ntiles; ++tile) {
        const int j0g = jbase + tile * BJ;

        // --- QK^T: 4 q-tiles x (jt, K-half) -> SS plane kh ---
        {
            f32x4 a0 = (f32x4){0,0,0,0}, a1 = (f32x4){0,0,0,0};
            f32x4 a2 = (f32x4){0,0,0,0}, a3 = (f32x4){0,0,0,0};
            #pragma unroll
            for (int kk = 0; kk < 4; ++kk) {
                half8 bf = Bc[kk];
                a0 = mfma16(Qf[0][kk], bf, a0);
                a1 = mfma16(Qf[1][kk], bf, a1);
                a2 = mfma16(Qf[2][kk], bf, a2);
                a3 = mfma16(Qf[3][kk], bf, a3);
            }
            float* ssp = (float*)(smem + SS_OFF) + kh * 2304;
            #pragma unroll
            for (int r = 0; r < 4; ++r) {
                ssp[(0  + quad * 4 + r) * 36 + jt * 16 + mn] = a0[r];
                ssp[(16 + quad * 4 + r) * 36 + jt * 16 + mn] = a1[r];
                ssp[(32 + quad * 4 + r) * 36 + jt * 16 + mn] = a2[r];
                ssp[(48 + quad * 4 + r) * 36 + jt * 16 + mn] = a3[r];
            }
        }
        __syncthreads();   // b1: SS visible

        // --- register prefetch (latency hidden by softmax) ---
        if (tile + 1 < ntiles) {
            const short* nb = mhb0 + (size_t)(tile + 1) * (BJ * EMBED);
            #pragma unroll
            for (int kk = 0; kk < 4; ++kk) Bn[kk] = *(const half8*)(nb + kk * 32);
        }
        {
            const short* mtb = MtG + (size_t)(jb32 + tile) * (BJ * EMBED);
            #pragma unroll
            for (int dt = 0; dt < 4; ++dt)
                Mtf[dt] = *(const half8*)(mtb + (dq * 64 + dt * 16 + mn) * BJ + quad * 8);
        }

        // --- online softmax ---
        {
            const float* p0 = (const float*)(smem + SS_OFF) + sq * 36 + 8 * sh;
            float4 sa = *(const float4*)p0;
            float4 sb = *(const float4*)(p0 + 4);
            float4 sc = *(const float4*)(p0 + 2304);
            float4 sd = *(const float4*)(p0 + 2308);
            float sv[8] = {sa.x + sc.x, sa.y + sc.y, sa.z + sc.z, sa.w + sc.w,
                           sb.x + sd.x, sb.y + sd.y, sb.z + sd.z, sb.w + sd.w};
            const int qg = q0 + sq;
            if (iseval) {
                if (qg == 0) {
                    #pragma unroll
                    for (int i = 0; i < 8; ++i) sv[i] = 0.f;
                }
            } else {
                int dj = qg - j0g - 8 * sh;
                #pragma unroll
                for (int i = 0; i < 8; ++i) if (dj == i) sv[i] = 0.f;
            }
            float mx = sv[0];
            #pragma unroll
            for (int i = 1; i < 8; ++i) mx = fmaxf(mx, sv[i]);
            mx = fmaxf(mx, __shfl_xor(mx, 1));
            mx = fmaxf(mx, __shfl_xor(mx, 2));
            float m_old = MS[sq];
            float m_new = fmaxf(m_old, mx);
            float alpha = __expf(m_old - m_new);
            float p[8], ps = 0.f;
            #pragma unroll
            for (int i = 0; i < 8; ++i) { p[i] = __expf(sv[i] - m_new); ps += p[i]; }
            ps += __shfl_xor(ps, 1);
            ps += __shfl_xor(ps, 2);
            if (sh == 0) {
                MS[sq] = m_new;
                AS[sq] = alpha;
                LS[sq] = LS[sq] * alpha + ps;
                if (m_new > m_old) AFLAG[tile & 1] = 1;   // benign write race
            }
            if (t == 0) AFLAG[(tile + 1) & 1] = 0;        // reset far slot
            half8 ph;
            #pragma unroll
            for (int i = 0; i < 8; ++i) ph[i] = (_Float16)p[i];
            *(half8*)(smem + PH_OFF + sq * 80 + sh * 16) = ph;
        }
        __syncthreads();   // b2: PH/AS/AFLAG visible

        // --- PV with alpha-skip ---
        {
            const bool need = AFLAG[tile & 1] != 0;       // block-uniform
            #pragma unroll
            for (int qi = 0; qi < 4; ++qi) {
                half8 pf = *(const half8*)(smem + PH_OFF + (qi * 16 + mn) * 80 + quad * 16);
                if (need) {
                    f32x4 al = *(const f32x4*)((const float*)(smem + AS_OFF) + qi * 16 + quad * 4);
                    #pragma unroll
                    for (int dt = 0; dt < 4; ++dt) {
                        f32x4 o = O[qi][dt];
                        o[0] *= al[0]; o[1] *= al[1]; o[2] *= al[2]; o[3] *= al[3];
                        O[qi][dt] = mfma16(pf, Mtf[dt], o);
                    }
                } else {
                    #pragma unroll
                    for (int dt = 0; dt < 4; ++dt)
                        O[qi][dt] = mfma16(pf, Mtf[dt], O[qi][dt]);
                }
            }
        }
        #pragma unroll
        for (int kk = 0; kk < 4; ++kk) Bc[kk] = Bn[kk];
    }

    // ---- epilogue: partial O (unnormalized) + (m,l) ----
    if (s == 0) {
        #pragma unroll
        for (int qi = 0; qi < 4; ++qi)
            #pragma unroll
            for (int dt = 0; dt < 4; ++dt) {
                int col = dq * 64 + dt * 16 + mn;
                #pragma unroll
                for (int r = 0; r < 4; ++r)
                    out[(size_t)(q0 + qi * 16 + quad * 4 + r) * EMBED + col] = O[qi][dt][r];
            }
    } else {
        short* dst = Ofp + (size_t)(s - 1) * n * EMBED;
        #pragma unroll
        for (int qi = 0; qi < 4; ++qi)
            #pragma unroll
            for (int dt = 0; dt < 4; ++dt) {
                int col = dq * 64 + dt * 16 + mn;
                #pragma unroll
                for (int r = 0; r < 4; ++r)
                    dst[(size_t)(q0 + qi * 16 + quad * 4 + r) * EMBED + col] = f2h(O[qi][dt][r]);
            }
    }
    if (t < BQ) {
        MLm[s * n + q0 + t] = MS[t];
        MLl[s * n + q0 + t] = LS[t];
    }

    // ---- last-arriving split merges all NS partials for this q-block ----
    __threadfence();                 // release our partial writes
    __syncthreads();
    if (t == 0) LASTW[0] = (atomicAdd(&cnt[qb], 1) == NS - 1);
    __syncthreads();
    if (!LASTW[0]) return;
    __threadfence();                 // acquire other splits' writes

    #pragma unroll 1
    for (int it = 0; it < 4; ++it) {
        const int row = q0 + it * 16 + (t >> 4);
        const int c = t & 15;
        float ms[NS], ls[NS];
        #pragma unroll
        for (int k = 0; k < NS; ++k) { ms[k] = MLm[k * n + row]; ls[k] = MLl[k * n + row]; }
        float m = ms[0];
        #pragma unroll
        for (int k = 1; k < NS; ++k) m = fmaxf(m, ms[k]);
        float w[NS], lsum = 0.f;
        #pragma unroll
        for (int k = 0; k < NS; ++k) { w[k] = __expf(ms[k] - m); lsum += w[k] * ls[k]; }
        float linv = 1.f / lsum;

        float acc[16];
        {
            const float4* o0 = (const float4*)(out + (size_t)row * EMBED + c * 16);
            #pragma unroll
            for (int i = 0; i < 4; ++i) {
                float4 v = o0[i];
                acc[4*i+0] = w[0] * v.x; acc[4*i+1] = w[0] * v.y;
                acc[4*i+2] = w[0] * v.z; acc[4*i+3] = w[0] * v.w;
            }
        }
        #pragma unroll
        for (int k = 1; k < NS; ++k) {
            const short* op = Ofp + (size_t)(k - 1) * n * EMBED + (size_t)row * EMBED + c * 16;
            half8 a = *(const half8*)op, b = *(const half8*)(op + 8);
            #pragma unroll
            for (int i = 0; i < 8; ++i) {
                acc[i]     += w[k] * (float)a[i];
                acc[8 + i] += w[k] * (float)b[i];
            }
        }
        float dot = 0.f;
        #pragma unroll
        for (int i = 0; i < 16; ++i) { acc[i] *= linv; dot += acc[i] * Wg[c * 16 + i]; }
        dot += __shfl_xor(dot, 1);
        dot += __shfl_xor(dot, 2);
        dot += __shfl_xor(dot, 4);
        dot += __shfl_xor(dot, 8);
        float g = 1.f / (1.f + __expf(-(dot + bg[0] + gb[0])));
        const float4* n4 = (const float4*)(Ng + (size_t)row * EMBED + c * 16);
        float4* o4 = (float4*)(out + (size_t)row * EMBED + c * 16);
        #pragma unroll
        for (int i = 0; i < 4; ++i) {
            float4 nn = n4[i];
            float4 res;
            res.x = acc[4*i+0] * g + nn.x * (1.f - g);
            res.y = acc[4*i+1] * g + nn.y * (1.f - g);
            res.z = acc[4*i+2] * g + nn.z * (1.f - g);
            res.w = acc[4*i+3] * g + nn.w * (1.f - g);
            o4[i] = res;
        }
    }
}

extern "C" void kernel_launch(void* const* d_in, const int* in_sizes, int n_in,
                              void* d_out, int out_size, void* d_ws, size_t ws_size,
                              hipStream_t stream) {
    const float* M      = (const float*)d_in[0];
    const float* N      = (const float*)d_in[1];
    const float* Wgp    = (const float*)d_in[2];
    const float* bgp    = (const float*)d_in[3];
    const float* gbp    = (const float*)d_in[4];
    const int*   iseval = (const int*)d_in[5];
    float* out = (float*)d_out;

    int n = in_sizes[0] / EMBED;   // 8192
    short* MhG = (short*)d_ws;                              // 4 MB
    short* MtG = MhG + (size_t)n * EMBED;                   // 4 MB
    short* Ofp = MtG + (size_t)n * EMBED;                   // 7 planes = 28 MB
    float* MLm = (float*)(Ofp + (size_t)(NS - 1) * n * EMBED);  // 8n f32
    float* MLl = MLm + (size_t)NS * n;                      // 8n f32
    int*   cnt = (int*)(MLl + (size_t)NS * n);              // 128 ints
    // ws required ~36.6 MB

    hipMemsetAsync(cnt, 0, (n / BQ) * sizeof(int), stream);
    hipLaunchKernelGGL(prep, dim3(n / 16), dim3(NT), 0, stream, M, MhG, MtG);
    hipLaunchKernelGGL(attn, dim3((n / BQ) * NS), dim3(NT), 0, stream,
                       MhG, MtG, N, Wgp, bgp, gbp, iseval, out, Ofp, MLm, MLl, cnt, n);
}

// Round 9
// 448.236 us; speedup vs baseline: 2.2538x; 2.2538x over previous
//
#include <hip/hip_runtime.h>

// AttentionMatcher R9 (= R8 minus the VGPR cap): direct-from-L2 B-operands,
// 8 XCD-pinned j-splits (grid 1024 -> ~4 blocks/CU at VGPR<=128), alpha-skip,
// in-kernel last-block combine. launch_bounds(256,2): R8's (256,4) capped
// VGPRs at 128 and spilled the K-loop to scratch (1.7 GB FETCH, 5x regress).
// out = gate * softmax(N M^T, diag<-0) M + (1-gate) * N,  n=8192, d=256, fp32.

constexpr int EMBED = 256;
constexpr int BQ = 64;
constexpr int BJ = 32;
constexpr int NT = 256;
constexpr int NS = 8;                // j-splits

constexpr int SS_OFF = 0;            // 2 planes x (64 x 36) f32 = 18432 B
constexpr int PH_OFF = 18432;        // 64 x 80 B (32 fp16 + pad)
constexpr int MS_OFF = 23552;
constexpr int LS_OFF = 23808;
constexpr int AS_OFF = 24064;
constexpr int AF_OFF = 24320;        // int aflag[2]
constexpr int LW_OFF = 24328;        // int last-flag
constexpr int LDS_SZ = 24332;        // x4 blocks/CU = 97.3 KB

typedef _Float16 half8 __attribute__((ext_vector_type(8)));
typedef float f32x4 __attribute__((ext_vector_type(4)));
typedef short short8v __attribute__((ext_vector_type(8)));

static __device__ __forceinline__ f32x4 mfma16(half8 a, half8 b, f32x4 c) {
    return __builtin_amdgcn_mfma_f32_16x16x32_f16(a, b, c, 0, 0, 0);
}
static __device__ __forceinline__ short f2h(float x) {
    return (short)__builtin_bit_cast(unsigned short, (_Float16)x);
}

// ---------- prep: fp16 row plane + fp16 transposed tile plane ----------
__global__ void prep(const float* __restrict__ M,
                     short* __restrict__ MhG, short* __restrict__ MtG) {
    __shared__ float L[16 * 260];
    const int r0 = blockIdx.x * 16;
    const int t = threadIdx.x;
    const int pj = t >> 4, pc = (t & 15) * 16;
    {
        const float* src = M + (size_t)(r0 + pj) * EMBED + pc;
        float4 v[4];
        #pragma unroll
        for (int i = 0; i < 4; ++i) v[i] = ((const float4*)src)[i];
        short* hd = MhG + (size_t)(r0 + pj) * EMBED + pc;
        #pragma unroll
        for (int i = 0; i < 2; ++i) {
            float4 a = v[2 * i], b = v[2 * i + 1];
            short8v h;
            h[0]=f2h(a.x); h[1]=f2h(a.y); h[2]=f2h(a.z); h[3]=f2h(a.w);
            h[4]=f2h(b.x); h[5]=f2h(b.y); h[6]=f2h(b.z); h[7]=f2h(b.w);
            *(short8v*)(hd + 8 * i) = h;
        }
        #pragma unroll
        for (int i = 0; i < 4; ++i)
            *(float4*)(L + pj * 260 + pc + 4 * i) = v[i];
    }
    __syncthreads();
    {
        const int d = t;
        const int tile = r0 >> 5, jh = (r0 >> 4) & 1;
        short* dst = MtG + (size_t)tile * (BJ * EMBED) + d * BJ + jh * 16;
        #pragma unroll
        for (int g2 = 0; g2 < 2; ++g2) {
            short8v w;
            #pragma unroll
            for (int e = 0; e < 8; ++e) w[e] = f2h(L[(g2 * 8 + e) * 260 + d]);
            *(short8v*)(dst + g2 * 8) = w;
        }
    }
}

// ---------- fused flash attention + last-block combine ----------
__launch_bounds__(NT, 2)
__global__ void attn(const short* __restrict__ MhG, const short* __restrict__ MtG,
                     const float* __restrict__ Ng, const float* __restrict__ Wg,
                     const float* __restrict__ bg, const float* __restrict__ gb,
                     const int* __restrict__ iseval_p,
                     float* __restrict__ out, short* __restrict__ Ofp,
                     float* __restrict__ MLm, float* __restrict__ MLl,
                     int* __restrict__ cnt, int n)
{
    __shared__ __align__(16) char smem[LDS_SZ];
    float* MS = (float*)(smem + MS_OFF);
    float* LS = (float*)(smem + LS_OFF);
    float* AS = (float*)(smem + AS_OFF);
    int* AFLAG = (int*)(smem + AF_OFF);
    int* LASTW = (int*)(smem + LW_OFF);

    const int t = threadIdx.x, lane = t & 63, wave = t >> 6;
    const int quad = lane >> 4, mn = lane & 15;
    const int bid = blockIdx.x;
    const int s  = bid & (NS - 1);               // split == XCD (bid%8 pinning)
    const int qb = bid >> 3;                     // 0..127
    const int q0 = qb * BQ;
    const int jbase = s * (n / NS);
    const int jb32 = jbase / BJ;
    const int ntiles = (n / NS) / BJ;            // 32
    const int iseval = *iseval_p;
    const int jt = wave & 1, kh = wave >> 1;     // QK roles
    const int dq = wave;                         // PV d-quarter
    const int sq = t >> 2, sh = t & 3;           // softmax roles

    if (t < BQ) { MS[t] = -1e30f; LS[t] = 0.f; }
    if (t < 2) AFLAG[t] = 1;

    // ---- Q fragments fp16 (A-layout): this wave's K-half ----
    half8 Qf[4][4];
    #pragma unroll
    for (int qi = 0; qi < 4; ++qi) {
        const float* np = Ng + (size_t)(q0 + qi * 16 + mn) * EMBED;
        #pragma unroll
        for (int kk = 0; kk < 4; ++kk) {
            const float* p = np + (kh * 4 + kk) * 32 + quad * 8;
            float4 a = *(const float4*)p, b = *(const float4*)(p + 4);
            half8 h;
            h[0]=(_Float16)a.x; h[1]=(_Float16)a.y; h[2]=(_Float16)a.z; h[3]=(_Float16)a.w;
            h[4]=(_Float16)b.x; h[5]=(_Float16)b.y; h[6]=(_Float16)b.z; h[7]=(_Float16)b.w;
            Qf[qi][kk] = h;
        }
    }

    f32x4 O[4][4];
    #pragma unroll
    for (int qi = 0; qi < 4; ++qi)
        #pragma unroll
        for (int dt = 0; dt < 4; ++dt) O[qi][dt] = (f32x4){0.f, 0.f, 0.f, 0.f};

    const short* mhb0 = MhG + (size_t)(jbase + jt * 16 + mn) * EMBED + kh * 128 + quad * 8;
    half8 Bc[4], Bn[4], Mtf[4];
    #pragma unroll
    for (int kk = 0; kk < 4; ++kk) Bc[kk] = *(const half8*)(mhb0 + kk * 32);

    __syncthreads();

    for (int tile = 0; tile < ntiles; ++tile) {
        const int j0g = jbase + tile * BJ;

        // --- QK^T: 4 q-tiles x (jt, K-half) -> SS plane kh ---
        {
            f32x4 a0 = (f32x4){0,0,0,0}, a1 = (f32x4){0,0,0,0};
            f32x4 a2 = (f32x4){0,0,0,0}, a3 = (f32x4){0,0,0,0};
            #pragma unroll
            for (int kk = 0; kk < 4; ++kk) {
                half8 bf = Bc[kk];
                a0 = mfma16(Qf[0][kk], bf, a0);
                a1 = mfma16(Qf[1][kk], bf, a1);
                a2 = mfma16(Qf[2][kk], bf, a2);
                a3 = mfma16(Qf[3][kk], bf, a3);
            }
            float* ssp = (float*)(smem + SS_OFF) + kh * 2304;
            #pragma unroll
            for (int r = 0; r < 4; ++r) {
                ssp[(0  + quad * 4 + r) * 36 + jt * 16 + mn] = a0[r];
                ssp[(16 + quad * 4 + r) * 36 + jt * 16 + mn] = a1[r];
                ssp[(32 + quad * 4 + r) * 36 + jt * 16 + mn] = a2[r];
                ssp[(48 + quad * 4 + r) * 36 + jt * 16 + mn] = a3[r];
            }
        }
        __syncthreads();   // b1: SS visible

        // --- register prefetch (latency hidden by softmax) ---
        if (tile + 1 < ntiles) {
            const short* nb = mhb0 + (size_t)(tile + 1) * (BJ * EMBED);
            #pragma unroll
            for (int kk = 0; kk < 4; ++kk) Bn[kk] = *(const half8*)(nb + kk * 32);
        }
        {
            const short* mtb = MtG + (size_t)(jb32 + tile) * (BJ * EMBED);
            #pragma unroll
            for (int dt = 0; dt < 4; ++dt)
                Mtf[dt] = *(const half8*)(mtb + (dq * 64 + dt * 16 + mn) * BJ + quad * 8);
        }

        // --- online softmax ---
        {
            const float* p0 = (const float*)(smem + SS_OFF) + sq * 36 + 8 * sh;
            float4 sa = *(const float4*)p0;
            float4 sb = *(const float4*)(p0 + 4);
            float4 sc = *(const float4*)(p0 + 2304);
            float4 sd = *(const float4*)(p0 + 2308);
            float sv[8] = {sa.x + sc.x, sa.y + sc.y, sa.z + sc.z, sa.w + sc.w,
                           sb.x + sd.x, sb.y + sd.y, sb.z + sd.z, sb.w + sd.w};
            const int qg = q0 + sq;
            if (iseval) {
                if (qg == 0) {
                    #pragma unroll
                    for (int i = 0; i < 8; ++i) sv[i] = 0.f;
                }
            } else {
                int dj = qg - j0g - 8 * sh;
                #pragma unroll
                for (int i = 0; i < 8; ++i) if (dj == i) sv[i] = 0.f;
            }
            float mx = sv[0];
            #pragma unroll
            for (int i = 1; i < 8; ++i) mx = fmaxf(mx, sv[i]);
            mx = fmaxf(mx, __shfl_xor(mx, 1));
            mx = fmaxf(mx, __shfl_xor(mx, 2));
            float m_old = MS[sq];
            float m_new = fmaxf(m_old, mx);
            float alpha = __expf(m_old - m_new);
            float p[8], ps = 0.f;
            #pragma unroll
            for (int i = 0; i < 8; ++i) { p[i] = __expf(sv[i] - m_new); ps += p[i]; }
            ps += __shfl_xor(ps, 1);
            ps += __shfl_xor(ps, 2);
            if (sh == 0) {
                MS[sq] = m_new;
                AS[sq] = alpha;
                LS[sq] = LS[sq] * alpha + ps;
                if (m_new > m_old) AFLAG[tile & 1] = 1;   // benign write race
            }
            if (t == 0) AFLAG[(tile + 1) & 1] = 0;        // reset far slot
            half8 ph;
            #pragma unroll
            for (int i = 0; i < 8; ++i) ph[i] = (_Float16)p[i];
            *(half8*)(smem + PH_OFF + sq * 80 + sh * 16) = ph;
        }
        __syncthreads();   // b2: PH/AS/AFLAG visible

        // --- PV with alpha-skip ---
        {
            const bool need = AFLAG[tile & 1] != 0;       // block-uniform
            #pragma unroll
            for (int qi = 0; qi < 4; ++qi) {
                half8 pf = *(const half8*)(smem + PH_OFF + (qi * 16 + mn) * 80 + quad * 16);
                if (need) {
                    f32x4 al = *(const f32x4*)((const float*)(smem + AS_OFF) + qi * 16 + quad * 4);
                    #pragma unroll
                    for (int dt = 0; dt < 4; ++dt) {
                        f32x4 o = O[qi][dt];
                        o[0] *= al[0]; o[1] *= al[1]; o[2] *= al[2]; o[3] *= al[3];
                        O[qi][dt] = mfma16(pf, Mtf[dt], o);
                    }
                } else {
                    #pragma unroll
                    for (int dt = 0; dt < 4; ++dt)
                        O[qi][dt] = mfma16(pf, Mtf[dt], O[qi][dt]);
                }
            }
        }
        #pragma unroll
        for (int kk = 0; kk < 4; ++kk) Bc[kk] = Bn[kk];
    }

    // ---- epilogue: partial O (unnormalized) + (m,l) ----
    if (s == 0) {
        #pragma unroll
        for (int qi = 0; qi < 4; ++qi)
            #pragma unroll
            for (int dt = 0; dt < 4; ++dt) {
                int col = dq * 64 + dt * 16 + mn;
                #pragma unroll
                for (int r = 0; r < 4; ++r)
                    out[(size_t)(q0 + qi * 16 + quad * 4 + r) * EMBED + col] = O[qi][dt][r];
            }
    } else {
        short* dst = Ofp + (size_t)(s - 1) * n * EMBED;
        #pragma unroll
        for (int qi = 0; qi < 4; ++qi)
            #pragma unroll
            for (int dt = 0; dt < 4; ++dt) {
                int col = dq * 64 + dt * 16 + mn;
                #pragma unroll
                for (int r = 0; r < 4; ++r)
                    dst[(size_t)(q0 + qi * 16 + quad * 4 + r) * EMBED + col] = f2h(O[qi][dt][r]);
            }
    }
    if (t < BQ) {
        MLm[s * n + q0 + t] = MS[t];
        MLl[s * n + q0 + t] = LS[t];
    }

    // ---- last-arriving split merges all NS partials for this q-block ----
    __threadfence();                 // release our partial writes
    __syncthreads();
    if (t == 0) LASTW[0] = (atomicAdd(&cnt[qb], 1) == NS - 1);
    __syncthreads();
    if (!LASTW[0]) return;
    __threadfence();                 // acquire other splits' writes

    #pragma unroll 1
    for (int it = 0; it < 4; ++it) {
        const int row = q0 + it * 16 + (t >> 4);
        const int c = t & 15;
        float ms[NS], ls[NS];
        #pragma unroll
        for (int k = 0; k < NS; ++k) { ms[k] = MLm[k * n + row]; ls[k] = MLl[k * n + row]; }
        float m = ms[0];
        #pragma unroll
        for (int k = 1; k < NS; ++k) m = fmaxf(m, ms[k]);
        float w[NS], lsum = 0.f;
        #pragma unroll
        for (int k = 0; k < NS; ++k) { w[k] = __expf(ms[k] - m); lsum += w[k] * ls[k]; }
        float linv = 1.f / lsum;

        float acc[16];
        {
            const float4* o0 = (const float4*)(out + (size_t)row * EMBED + c * 16);
            #pragma unroll
            for (int i = 0; i < 4; ++i) {
                float4 v = o0[i];
                acc[4*i+0] = w[0] * v.x; acc[4*i+1] = w[0] * v.y;
                acc[4*i+2] = w[0] * v.z; acc[4*i+3] = w[0] * v.w;
            }
        }
        #pragma unroll
        for (int k = 1; k < NS; ++k) {
            const short* op = Ofp + (size_t)(k - 1) * n * EMBED + (size_t)row * EMBED + c * 16;
            half8 a = *(const half8*)op, b = *(const half8*)(op + 8);
            #pragma unroll
            for (int i = 0; i < 8; ++i) {
                acc[i]     += w[k] * (float)a[i];
                acc[8 + i] += w[k] * (float)b[i];
            }
        }
        float dot = 0.f;
        #pragma unroll
        for (int i = 0; i < 16; ++i) { acc[i] *= linv; dot += acc[i] * Wg[c * 16 + i]; }
        dot += __shfl_xor(dot, 1);
        dot += __shfl_xor(dot, 2);
        dot += __shfl_xor(dot, 4);
        dot += __shfl_xor(dot, 8);
        float g = 1.f / (1.f + __expf(-(dot + bg[0] + gb[0])));
        const float4* n4 = (const float4*)(Ng + (size_t)row * EMBED + c * 16);
        float4* o4 = (float4*)(out + (size_t)row * EMBED + c * 16);
        #pragma unroll
        for (int i = 0; i < 4; ++i) {
            float4 nn = n4[i];
            float4 res;
            res.x = acc[4*i+0] * g + nn.x * (1.f - g);
            res.y = acc[4*i+1] * g + nn.y * (1.f - g);
            res.z = acc[4*i+2] * g + nn.z * (1.f - g);
            res.w = acc[4*i+3] * g + nn.w * (1.f - g);
            o4[i] = res;
        }
    }
}

extern "C" void kernel_launch(void* const* d_in, const int* in_sizes, int n_in,
                              void* d_out, int out_size, void* d_ws, size_t ws_size,
                              hipStream_t stream) {
    const float* M      = (const float*)d_in[0];
    const float* N      = (const float*)d_in[1];
    const float* Wgp    = (const float*)d_in[2];
    const float* bgp    = (const float*)d_in[3];
    const float* gbp    = (const float*)d_in[4];
    const int*   iseval = (const int*)d_in[5];
    float* out = (float*)d_out;

    int n = in_sizes[0] / EMBED;   // 8192
    short* MhG = (short*)d_ws;                              // 4 MB
    short* MtG = MhG + (size_t)n * EMBED;                   // 4 MB
    short* Ofp = MtG + (size_t)n * EMBED;                   // 7 planes = 28 MB
    float* MLm = (float*)(Ofp + (size_t)(NS - 1) * n * EMBED);  // 8n f32
    float* MLl = MLm + (size_t)NS * n;                      // 8n f32
    int*   cnt = (int*)(MLl + (size_t)NS * n);              // 128 ints
    // ws required ~36.6 MB

    hipMemsetAsync(cnt, 0, (n / BQ) * sizeof(int), stream);
    hipLaunchKernelGGL(prep, dim3(n / 16), dim3(NT), 0, stream, M, MhG, MtG);
    hipLaunchKernelGGL(attn, dim3((n / BQ) * NS), dim3(NT), 0, stream,
                       MhG, MtG, N, Wgp, bgp, gbp, iseval, out, Ofp, MLm, MLl, cnt, n);
}

// Round 10
// 202.636 us; speedup vs baseline: 4.9854x; 2.2120x over previous
//
#include <hip/hip_runtime.h>

// AttentionMatcher R10: R7's proven 3-kernel structure + 8 XCD-pinned splits
// (grid 1024 -> 4 blocks/CU at VGPR<=128). No in-kernel combine, no fences
// (R9: device-scope __threadfence on non-coherent XCD L2s forced 28MB of
// partials through HBM inside the hot loop -> 4x regress), no alpha-skip.
// out = gate * softmax(N M^T, diag<-0) M + (1-gate) * N,  n=8192, d=256, fp32.
//
// ws: MhG [n][256] fp16 row-major            (QK B-plane)
//     MtG [n/32 tiles][256 d][32 j] fp16     (PV B-plane, transposed)
//     Ofp 7 fp16 partial O planes (splits 1..7); split-0 partial f32 in d_out
//     MLm/MLl [8][n] f32 running max / sum per split.

constexpr int EMBED = 256;
constexpr int BQ = 64;
constexpr int BJ = 32;
constexpr int NT = 256;
constexpr int NS = 8;                // j-splits

constexpr int SS_OFF = 0;            // 2 planes x (64 x 36) f32 = 18432 B
constexpr int PH_OFF = 18432;        // 64 x 80 B (32 fp16 + pad)
constexpr int MS_OFF = 23552;
constexpr int LS_OFF = 23808;
constexpr int AS_OFF = 24064;
constexpr int LDS_SZ = 24320;        // x4 blocks/CU = 97.3 KB

typedef _Float16 half8 __attribute__((ext_vector_type(8)));
typedef float f32x4 __attribute__((ext_vector_type(4)));
typedef short short8v __attribute__((ext_vector_type(8)));

static __device__ __forceinline__ f32x4 mfma16(half8 a, half8 b, f32x4 c) {
    return __builtin_amdgcn_mfma_f32_16x16x32_f16(a, b, c, 0, 0, 0);
}
static __device__ __forceinline__ short f2h(float x) {
    return (short)__builtin_bit_cast(unsigned short, (_Float16)x);
}

// ---------- prep: fp16 row plane + fp16 transposed tile plane ----------
__global__ void prep(const float* __restrict__ M,
                     short* __restrict__ MhG, short* __restrict__ MtG) {
    __shared__ float L[16 * 260];
    const int r0 = blockIdx.x * 16;
    const int t = threadIdx.x;
    const int pj = t >> 4, pc = (t & 15) * 16;
    {
        const float* src = M + (size_t)(r0 + pj) * EMBED + pc;
        float4 v[4];
        #pragma unroll
        for (int i = 0; i < 4; ++i) v[i] = ((const float4*)src)[i];
        short* hd = MhG + (size_t)(r0 + pj) * EMBED + pc;
        #pragma unroll
        for (int i = 0; i < 2; ++i) {
            float4 a = v[2 * i], b = v[2 * i + 1];
            short8v h;
            h[0]=f2h(a.x); h[1]=f2h(a.y); h[2]=f2h(a.z); h[3]=f2h(a.w);
            h[4]=f2h(b.x); h[5]=f2h(b.y); h[6]=f2h(b.z); h[7]=f2h(b.w);
            *(short8v*)(hd + 8 * i) = h;
        }
        #pragma unroll
        for (int i = 0; i < 4; ++i)
            *(float4*)(L + pj * 260 + pc + 4 * i) = v[i];
    }
    __syncthreads();
    {
        const int d = t;
        const int tile = r0 >> 5, jh = (r0 >> 4) & 1;
        short* dst = MtG + (size_t)tile * (BJ * EMBED) + d * BJ + jh * 16;
        #pragma unroll
        for (int g2 = 0; g2 < 2; ++g2) {
            short8v w;
            #pragma unroll
            for (int e = 0; e < 8; ++e) w[e] = f2h(L[(g2 * 8 + e) * 260 + d]);
            *(short8v*)(dst + g2 * 8) = w;
        }
    }
}

// ---------- split-j flash kernel (direct-from-L2 B-operands) ----------
__launch_bounds__(NT, 2)
__global__ void attn(const short* __restrict__ MhG, const short* __restrict__ MtG,
                     const float* __restrict__ Ng, const int* __restrict__ iseval_p,
                     float* __restrict__ O0out, short* __restrict__ Ofp,
                     float* __restrict__ MLm, float* __restrict__ MLl, int n)
{
    __shared__ __align__(16) char smem[LDS_SZ];
    float* MS = (float*)(smem + MS_OFF);
    float* LS = (float*)(smem + LS_OFF);
    float* AS = (float*)(smem + AS_OFF);

    const int t = threadIdx.x, lane = t & 63, wave = t >> 6;
    const int quad = lane >> 4, mn = lane & 15;
    const int bid = blockIdx.x;
    const int s  = bid & (NS - 1);               // split == XCD (bid%8 pinning)
    const int qb = bid >> 3;                     // 0..127
    const int q0 = qb * BQ;
    const int jbase = s * (n / NS);
    const int jb32 = jbase / BJ;
    const int ntiles = (n / NS) / BJ;            // 32
    const int iseval = *iseval_p;
    const int jt = wave & 1, kh = wave >> 1;     // QK roles
    const int dq = wave;                         // PV d-quarter
    const int sq = t >> 2, sh = t & 3;           // softmax roles

    if (t < BQ) { MS[t] = -1e30f; LS[t] = 0.f; }

    // ---- Q fragments fp16 (A-layout): this wave's K-half ----
    half8 Qf[4][4];
    #pragma unroll
    for (int qi = 0; qi < 4; ++qi) {
        const float* np = Ng + (size_t)(q0 + qi * 16 + mn) * EMBED;
        #pragma unroll
        for (int kk = 0; kk < 4; ++kk) {
            const float* p = np + (kh * 4 + kk) * 32 + quad * 8;
            float4 a = *(const float4*)p, b = *(const float4*)(p + 4);
            half8 h;
            h[0]=(_Float16)a.x; h[1]=(_Float16)a.y; h[2]=(_Float16)a.z; h[3]=(_Float16)a.w;
            h[4]=(_Float16)b.x; h[5]=(_Float16)b.y; h[6]=(_Float16)b.z; h[7]=(_Float16)b.w;
            Qf[qi][kk] = h;
        }
    }

    f32x4 O[4][4];
    #pragma unroll
    for (int qi = 0; qi < 4; ++qi)
        #pragma unroll
        for (int dt = 0; dt < 4; ++dt) O[qi][dt] = (f32x4){0.f, 0.f, 0.f, 0.f};

    const short* mhb0 = MhG + (size_t)(jbase + jt * 16 + mn) * EMBED + kh * 128 + quad * 8;
    half8 Bc[4], Bn[4], Mtf[4];
    #pragma unroll
    for (int kk = 0; kk < 4; ++kk) Bc[kk] = *(const half8*)(mhb0 + kk * 32);

    __syncthreads();

    for (int tile = 0; tile < ntiles; ++tile) {
        const int j0g = jbase + tile * BJ;

        // --- QK^T: 4 q-tiles x (jt, K-half) -> SS plane kh ---
        {
            f32x4 a0 = (f32x4){0,0,0,0}, a1 = (f32x4){0,0,0,0};
            f32x4 a2 = (f32x4){0,0,0,0}, a3 = (f32x4){0,0,0,0};
            #pragma unroll
            for (int kk = 0; kk < 4; ++kk) {
                half8 bf = Bc[kk];
                a0 = mfma16(Qf[0][kk], bf, a0);
                a1 = mfma16(Qf[1][kk], bf, a1);
                a2 = mfma16(Qf[2][kk], bf, a2);
                a3 = mfma16(Qf[3][kk], bf, a3);
            }
            float* ssp = (float*)(smem + SS_OFF) + kh * 2304;
            #pragma unroll
            for (int r = 0; r < 4; ++r) {
                ssp[(0  + quad * 4 + r) * 36 + jt * 16 + mn] = a0[r];
                ssp[(16 + quad * 4 + r) * 36 + jt * 16 + mn] = a1[r];
                ssp[(32 + quad * 4 + r) * 36 + jt * 16 + mn] = a2[r];
                ssp[(48 + quad * 4 + r) * 36 + jt * 16 + mn] = a3[r];
            }
        }
        __syncthreads();   // b1: SS visible

        // --- register prefetch (latency hidden by softmax) ---
        if (tile + 1 < ntiles) {
            const short* nb = mhb0 + (size_t)(tile + 1) * (BJ * EMBED);
            #pragma unroll
            for (int kk = 0; kk < 4; ++kk) Bn[kk] = *(const half8*)(nb + kk * 32);
        }
        {
            const short* mtb = MtG + (size_t)(jb32 + tile) * (BJ * EMBED);
            #pragma unroll
            for (int dt = 0; dt < 4; ++dt)
                Mtf[dt] = *(const half8*)(mtb + (dq * 64 + dt * 16 + mn) * BJ + quad * 8);
        }

        // --- online softmax: thread (sq, sh) owns j = 8sh..8sh+7 ---
        {
            const float* p0 = (const float*)(smem + SS_OFF) + sq * 36 + 8 * sh;
            float4 sa = *(const float4*)p0;
            float4 sb = *(const float4*)(p0 + 4);
            float4 sc = *(const float4*)(p0 + 2304);
            float4 sd = *(const float4*)(p0 + 2308);
            float sv[8] = {sa.x + sc.x, sa.y + sc.y, sa.z + sc.z, sa.w + sc.w,
                           sb.x + sd.x, sb.y + sd.y, sb.z + sd.z, sb.w + sd.w};
            const int qg = q0 + sq;
            if (iseval) {
                if (qg == 0) {
                    #pragma unroll
                    for (int i = 0; i < 8; ++i) sv[i] = 0.f;
                }
            } else {
                int dj = qg - j0g - 8 * sh;
                #pragma unroll
                for (int i = 0; i < 8; ++i) if (dj == i) sv[i] = 0.f;
            }
            float mx = sv[0];
            #pragma unroll
            for (int i = 1; i < 8; ++i) mx = fmaxf(mx, sv[i]);
            mx = fmaxf(mx, __shfl_xor(mx, 1));
            mx = fmaxf(mx, __shfl_xor(mx, 2));
            float m_old = MS[sq];
            float m_new = fmaxf(m_old, mx);
            float alpha = __expf(m_old - m_new);
            float p[8], ps = 0.f;
            #pragma unroll
            for (int i = 0; i < 8; ++i) { p[i] = __expf(sv[i] - m_new); ps += p[i]; }
            ps += __shfl_xor(ps, 1);
            ps += __shfl_xor(ps, 2);
            if (sh == 0) {
                MS[sq] = m_new;
                AS[sq] = alpha;
                LS[sq] = LS[sq] * alpha + ps;
            }
            half8 ph;
            #pragma unroll
            for (int i = 0; i < 8; ++i) ph[i] = (_Float16)p[i];
            *(half8*)(smem + PH_OFF + sq * 80 + sh * 16) = ph;
        }
        __syncthreads();   // b2: PH/AS visible

        // --- PV: 4 q-tiles x this wave's 4 d-tiles, K=32 ---
        #pragma unroll
        for (int qi = 0; qi < 4; ++qi) {
            half8 pf = *(const half8*)(smem + PH_OFF + (qi * 16 + mn) * 80 + quad * 16);
            f32x4 al = *(const f32x4*)((const float*)(smem + AS_OFF) + qi * 16 + quad * 4);
            #pragma unroll
            for (int dt = 0; dt < 4; ++dt) {
                f32x4 o = O[qi][dt];
                o[0] *= al[0]; o[1] *= al[1]; o[2] *= al[2]; o[3] *= al[3];
                O[qi][dt] = mfma16(pf, Mtf[dt], o);
            }
        }
        #pragma unroll
        for (int kk = 0; kk < 4; ++kk) Bc[kk] = Bn[kk];
        // SS rewrite (QK t+1) safe: softmax(t) finished before b2.
        // PH/AS rewrite (softmax t+1) fenced by b1(t+1), after PV(t).
    }

    // ---- epilogue: partial O (unnormalized) + (m,l) ----
    if (s == 0) {
        #pragma unroll
        for (int qi = 0; qi < 4; ++qi)
            #pragma unroll
            for (int dt = 0; dt < 4; ++dt) {
                int col = dq * 64 + dt * 16 + mn;
                #pragma unroll
                for (int r = 0; r < 4; ++r)
                    O0out[(size_t)(q0 + qi * 16 + quad * 4 + r) * EMBED + col] = O[qi][dt][r];
            }
    } else {
        short* dst = Ofp + (size_t)(s - 1) * n * EMBED;
        #pragma unroll
        for (int qi = 0; qi < 4; ++qi)
            #pragma unroll
            for (int dt = 0; dt < 4; ++dt) {
                int col = dq * 64 + dt * 16 + mn;
                #pragma unroll
                for (int r = 0; r < 4; ++r)
                    dst[(size_t)(q0 + qi * 16 + quad * 4 + r) * EMBED + col] = f2h(O[qi][dt][r]);
            }
    }
    if (t < BQ) {
        MLm[s * n + q0 + t] = MS[t];
        MLl[s * n + q0 + t] = LS[t];
    }
}

// ---------- combine 8 partials + gate + blend ----------
__global__ void combine8(const float* __restrict__ O0, const short* __restrict__ Ofp,
                         const float* __restrict__ MLm, const float* __restrict__ MLl,
                         const float* __restrict__ Ng, const float* __restrict__ Wg,
                         const float* __restrict__ bg, const float* __restrict__ gb,
                         float* __restrict__ out, int n)
{
    const int t = threadIdx.x;
    const int row = blockIdx.x * 16 + (t >> 4);
    const int c = t & 15;
    float ms[NS], ls[NS];
    #pragma unroll
    for (int k = 0; k < NS; ++k) { ms[k] = MLm[k * n + row]; ls[k] = MLl[k * n + row]; }
    float m = ms[0];
    #pragma unroll
    for (int k = 1; k < NS; ++k) m = fmaxf(m, ms[k]);
    float w[NS], lsum = 0.f;
    #pragma unroll
    for (int k = 0; k < NS; ++k) { w[k] = __expf(ms[k] - m); lsum += w[k] * ls[k]; }
    float linv = 1.f / lsum;

    float acc[16];
    {
        const float4* o0 = (const float4*)(O0 + (size_t)row * EMBED + c * 16);
        #pragma unroll
        for (int i = 0; i < 4; ++i) {
            float4 v = o0[i];
            acc[4*i+0] = w[0] * v.x; acc[4*i+1] = w[0] * v.y;
            acc[4*i+2] = w[0] * v.z; acc[4*i+3] = w[0] * v.w;
        }
    }
    #pragma unroll
    for (int k = 1; k < NS; ++k) {
        const short* op = Ofp + (size_t)(k - 1) * n * EMBED + (size_t)row * EMBED + c * 16;
        half8 a = *(const half8*)op, b = *(const half8*)(op + 8);
        #pragma unroll
        for (int i = 0; i < 8; ++i) {
            acc[i]     += w[k] * (float)a[i];
            acc[8 + i] += w[k] * (float)b[i];
        }
    }
    float dot = 0.f;
    #pragma unroll
    for (int i = 0; i < 16; ++i) { acc[i] *= linv; dot += acc[i] * Wg[c * 16 + i]; }
    dot += __shfl_xor(dot, 1);
    dot += __shfl_xor(dot, 2);
    dot += __shfl_xor(dot, 4);
    dot += __shfl_xor(dot, 8);
    float g = 1.f / (1.f + __expf(-(dot + bg[0] + gb[0])));
    const float4* n4 = (const float4*)(Ng + (size_t)row * EMBED + c * 16);
    float4* o4 = (float4*)(out + (size_t)row * EMBED + c * 16);
    #pragma unroll
    for (int i = 0; i < 4; ++i) {
        float4 nn = n4[i];
        float4 res;
        res.x = acc[4*i+0] * g + nn.x * (1.f - g);
        res.y = acc[4*i+1] * g + nn.y * (1.f - g);
        res.z = acc[4*i+2] * g + nn.z * (1.f - g);
        res.w = acc[4*i+3] * g + nn.w * (1.f - g);
        o4[i] = res;
    }
}

extern "C" void kernel_launch(void* const* d_in, const int* in_sizes, int n_in,
                              void* d_out, int out_size, void* d_ws, size_t ws_size,
                              hipStream_t stream) {
    const float* M      = (const float*)d_in[0];
    const float* N      = (const float*)d_in[1];
    const float* Wgp    = (const float*)d_in[2];
    const float* bgp    = (const float*)d_in[3];
    const float* gbp    = (const float*)d_in[4];
    const int*   iseval = (const int*)d_in[5];
    float* out = (float*)d_out;

    int n = in_sizes[0] / EMBED;   // 8192
    short* MhG = (short*)d_ws;                              // 4 MB
    short* MtG = MhG + (size_t)n * EMBED;                   // 4 MB
    short* Ofp = MtG + (size_t)n * EMBED;                   // 7 planes = 28 MB
    float* MLm = (float*)(Ofp + (size_t)(NS - 1) * n * EMBED);  // 8n f32
    float* MLl = MLm + (size_t)NS * n;                      // 8n f32
    // ws required ~36.6 MB (fits: R8/R9 ran with this layout)

    hipLaunchKernelGGL(prep, dim3(n / 16), dim3(NT), 0, stream, M, MhG, MtG);
    hipLaunchKernelGGL(attn, dim3((n / BQ) * NS), dim3(NT), 0, stream,
                       MhG, MtG, N, iseval, out, Ofp, MLm, MLl, n);
    hipLaunchKernelGGL(combine8, dim3(n / 16), dim3(NT), 0, stream,
                       out, Ofp, MLm, MLl, N, Wgp, bgp, gbp, out, n);
}